// Round 1
// baseline (11068.682 us; speedup 1.0000x reference)
//
#include <hip/hip_runtime.h>
#include <hip/hip_bf16.h>

#define BB 256
#define TT 512
#define DD 512
#define HH 1024
#define OO 512

typedef unsigned short u16;
typedef unsigned int u32;
typedef unsigned long long u64;
typedef __attribute__((ext_vector_type(8))) short frag8;
typedef __attribute__((ext_vector_type(4))) float floatx4;

__device__ __forceinline__ u16 f2b(float f) {
  union { float f; u32 u; } v; v.f = f;
  u32 r = v.u + 0x7fffu + ((v.u >> 16) & 1u);
  return (u16)(r >> 16);
}
__device__ __forceinline__ float b2f(u16 b) {
  union { u32 u; float f; } v; v.u = ((u32)b) << 16; return v.f;
}
__device__ __forceinline__ float fast_tanh(float x) {
  // tanh(x) = 1 - 2/(exp(2x)+1); saturates correctly at +/-inf
  float e = __expf(2.0f * x);
  return 1.0f - 2.0f / (e + 1.0f);
}

// transpose f32 [K][N] -> bf16 [N][K]
__global__ void k_transpose(const float* __restrict__ src, u16* __restrict__ dst,
                            int K, int N) {
  int idx = blockIdx.x * 256 + threadIdx.x;
  if (idx >= K * N) return;
  int k = idx / N, n = idx - k * N;
  dst[(u64)n * K + k] = f2b(src[idx]);
}

__global__ void k_init_s0(const float* __restrict__ h0, u16* __restrict__ S) {
  int idx = blockIdx.x * 256 + threadIdx.x;
  if (idx < BB * HH) S[idx] = f2b(h0[idx]);
}

__global__ void k_final_h(const u16* __restrict__ Sl, float* __restrict__ out) {
  int idx = blockIdx.x * 256 + threadIdx.x;
  if (idx < BB * HH) out[idx] = b2f(Sl[idx]);
}

__global__ void k_zero_flags(int* __restrict__ flags, int n) {
  int idx = blockIdx.x * 256 + threadIdx.x;
  if (idx < n) flags[idx] = 0;
}

// ---------------------------------------------------------------------------
// GEMM1: Z = X @ W_xh.  X f32 [B*T, D] row-major (m = b*T + t).
// Wt bf16 [N=HH][K=DD].  Output scattered bf16 into S[t+1][b][col].
// ---------------------------------------------------------------------------
__global__ __launch_bounds__(256) void k_gemm_xh(const float* __restrict__ X,
                                                 const u16* __restrict__ Wt,
                                                 u16* __restrict__ S) {
  __shared__ __align__(16) u16 As[64 * 72];
  __shared__ __align__(16) u16 Bs[64 * 72];
  const int tid = threadIdx.x;
  const int m0 = blockIdx.x * 64, n0 = blockIdx.y * 64;
  const int lane = tid & 63, wv = tid >> 6;
  const int fr = lane & 15, quad = lane >> 4;

  floatx4 acc[4];
#pragma unroll
  for (int i = 0; i < 4; ++i) acc[i] = (floatx4){0.f, 0.f, 0.f, 0.f};

  for (int kc = 0; kc < DD; kc += 64) {
    const float* Ab = X + (u64)m0 * DD + kc;
#pragma unroll
    for (int it = 0; it < 4; ++it) {
      int linear = (it * 256 + tid) * 4;
      int r = linear >> 6, c = linear & 63;
      float4 v = *(const float4*)(Ab + (u64)r * DD + c);
      ushort4 o;
      o.x = f2b(v.x); o.y = f2b(v.y); o.z = f2b(v.z); o.w = f2b(v.w);
      *(ushort4*)&As[r * 72 + c] = o;
    }
    const u16* Bb = Wt + (u64)n0 * DD + kc;
#pragma unroll
    for (int it = 0; it < 2; ++it) {
      int linear = (it * 256 + tid) * 8;
      int n = linear >> 6, c = linear & 63;
      *(uint4*)&Bs[n * 72 + c] = *(const uint4*)(Bb + (u64)n * DD + c);
    }
    __syncthreads();
#pragma unroll
    for (int kk = 0; kk < 64; kk += 32) {
      frag8 bf = *(const frag8*)&Bs[(wv * 16 + fr) * 72 + kk + quad * 8];
#pragma unroll
      for (int i = 0; i < 4; ++i) {
        frag8 af = *(const frag8*)&As[(i * 16 + fr) * 72 + kk + quad * 8];
        acc[i] = __builtin_amdgcn_mfma_f32_16x16x32_bf16(af, bf, acc[i], 0, 0, 0);
      }
    }
    __syncthreads();
  }
  const int col = n0 + wv * 16 + fr;
#pragma unroll
  for (int i = 0; i < 4; ++i) {
#pragma unroll
    for (int r = 0; r < 4; ++r) {
      int m = m0 + i * 16 + quad * 4 + r;
      int t = m & (TT - 1);
      int b = m >> 9;  // m / TT
      S[((u64)(t + 1) * BB + b) * HH + col] = f2b(acc[i][r]);
    }
  }
}

// ---------------------------------------------------------------------------
// Persistent scan kernel: for t in 0..TT: S[t+1] = tanh(S[t] @ W_hh + S[t+1])
// Grid: 8 x 32 = 256 blocks (one per CU). Block (mb,nb) owns the 32x32 output
// tile (rows mb*32, cols nb*32) for ALL steps.
//
// v2 sync structure (flag-line decontention + per-wave fine-grained waits):
//  - W_hh slice lives in REGISTERS: wave wv holds cols n0..n0+32 x k-slice
//    [wv*256, wv*256+256) as 16 frag8 (64 VGPRs). No LDS for W.
//  - A fragments gathered DIRECTLY global->VGPR (each element consumed by
//    exactly one lane in this K-split decomposition -> LDS staging is pure
//    overhead). No LDS for A; no staging barrier.
//  - flags are PER-PRODUCER: flags[(t*8+mb)*32+nb] = 1 (plain release store,
//    no atomic RMW -> no serialized same-line far-atomic ping-pong).
//  - wave wv waits only on ITS 8 producers (nb = wv*8 .. wv*8+7): relaxed
//    uncached polls + one agent acquire fence on exit.
//  - Z (the gemm_xh pre-fill in S[t+1], own tile only) prefetched into regs
//    BEFORE the spin, hiding its latency under the wait.
// Only remaining LDS: 4-wave K-split reduction buffer (16.9 KB).
// ---------------------------------------------------------------------------
__global__ __launch_bounds__(256) void k_scan(const u16* __restrict__ Whh_t,
                                              u16* __restrict__ S,
                                              int* __restrict__ flags) {
  __shared__ float Red[4][32][33];

  const int tid = threadIdx.x;
  const int mb = blockIdx.x;   // 0..7  (row block)
  const int nb = blockIdx.y;   // 0..31 (col block)
  const int m0 = mb * 32, n0 = nb * 32;
  const int lane = tid & 63, wv = tid >> 6;
  const int fr = lane & 15, q = lane >> 4;
  const int kbase = wv * 256;

  // Hoist the invariant W_hh fragments into registers for the whole scan.
  // wb0[kt]: rows (cols of W_hh) n0+fr,    k = kbase + kt*32 + q*8 .. +8
  // wb1[kt]: rows n0+16+fr, same k
  frag8 wb0[8], wb1[8];
  {
    const u16* W0 = Whh_t + (u64)(n0 + fr) * HH + kbase + q * 8;
    const u16* W1 = Whh_t + (u64)(n0 + 16 + fr) * HH + kbase + q * 8;
#pragma unroll
    for (int kt = 0; kt < 8; ++kt) {
      wb0[kt] = *(const frag8*)(W0 + kt * 32);
      wb1[kt] = *(const frag8*)(W1 + kt * 32);
    }
  }

  for (int t = 0; t < TT; ++t) {
    u16* Sout = S + (u64)(t + 1) * BB * HH + (u64)m0 * HH + n0;

    // Prefetch Z (own output tile, written by gemm_xh; nobody else touches it)
    // -- issued before the spin so its latency hides under the wait.
    float zv[4];
#pragma unroll
    for (int i = 0; i < 4; ++i) {
      int elem = i * 256 + tid;
      int r = elem >> 5, c = elem & 31;
      zv[i] = b2f(Sout[(u64)r * HH + c]);
    }

    if (t > 0) {
      // Wave wv needs k in [wv*256, wv*256+256) of S[t] = cols produced by
      // blocks (mb, nb' = wv*8 .. wv*8+7) at step t-1.
      const int* fb = flags + ((u64)(t - 1) * 8 + mb) * 32;
      const int idx = wv * 8 + (lane & 7);
      while (__hip_atomic_load(&fb[idx], __ATOMIC_RELAXED,
                               __HIP_MEMORY_SCOPE_AGENT) == 0) {
        __builtin_amdgcn_s_sleep(1);
      }
      __builtin_amdgcn_fence(__ATOMIC_ACQUIRE, "agent");
    }

    // Gather A fragments directly global -> VGPR (no reuse across lanes:
    // each (row, 16B k-chunk) is read by exactly one lane; rows are 2KB
    // apart but each row's 512B k-slice is fully consumed -> no overfetch).
    const u16* St = S + (u64)t * BB * HH;
    const u16* A0 = St + (u64)(m0 + fr) * HH + kbase + q * 8;
    const u16* A1 = St + (u64)(m0 + 16 + fr) * HH + kbase + q * 8;
    frag8 a0[8], a1[8];
#pragma unroll
    for (int kt = 0; kt < 8; ++kt) {
      a0[kt] = *(const frag8*)(A0 + kt * 32);
      a1[kt] = *(const frag8*)(A1 + kt * 32);
    }

    floatx4 acc[2][2];
#pragma unroll
    for (int i = 0; i < 2; ++i)
#pragma unroll
      for (int j = 0; j < 2; ++j) acc[i][j] = (floatx4){0.f, 0.f, 0.f, 0.f};

#pragma unroll
    for (int kt = 0; kt < 8; ++kt) {
      acc[0][0] = __builtin_amdgcn_mfma_f32_16x16x32_bf16(a0[kt], wb0[kt], acc[0][0], 0, 0, 0);
      acc[0][1] = __builtin_amdgcn_mfma_f32_16x16x32_bf16(a0[kt], wb1[kt], acc[0][1], 0, 0, 0);
      acc[1][0] = __builtin_amdgcn_mfma_f32_16x16x32_bf16(a1[kt], wb0[kt], acc[1][0], 0, 0, 0);
      acc[1][1] = __builtin_amdgcn_mfma_f32_16x16x32_bf16(a1[kt], wb1[kt], acc[1][1], 0, 0, 0);
    }

    // Per-wave K-split partials -> LDS
#pragma unroll
    for (int im = 0; im < 2; ++im)
#pragma unroll
      for (int in = 0; in < 2; ++in)
#pragma unroll
        for (int r = 0; r < 4; ++r) {
          int row = im * 16 + q * 4 + r;
          int col = in * 16 + fr;
          Red[wv][row][col] = acc[im][in][r];
        }
    __syncthreads();

    // Reduce 4 partials, add prefetched Z, tanh, store bf16
#pragma unroll
    for (int i = 0; i < 4; ++i) {
      int elem = i * 256 + tid;
      int r = elem >> 5, c = elem & 31;
      float v = Red[0][r][c] + Red[1][r][c] + Red[2][r][c] + Red[3][r][c];
      Sout[(u64)r * HH + c] = f2b(fast_tanh(v + zv[i]));
    }
    __syncthreads();  // all waves' stores drained (vmcnt(0) at barrier)

    if (tid == 0) {
      // Release: wbl2 flushes the XCD L2 (covers all waves' stores, which
      // the barrier already drained into L2), then flag becomes visible.
      __hip_atomic_store(&flags[((u64)t * 8 + mb) * 32 + nb], 1,
                         __ATOMIC_RELEASE, __HIP_MEMORY_SCOPE_AGENT);
    }
  }
}

// ---------------------------------------------------------------------------
// GEMM3: Y = Hs @ W_hy.  Hs bf16 [T*B][HH] (m = t*B + b), Wt bf16 [OO][HH].
// ---------------------------------------------------------------------------
__global__ __launch_bounds__(256) void k_gemm_hy(const u16* __restrict__ Hs,
                                                 const u16* __restrict__ Wt,
                                                 float* __restrict__ out) {
  __shared__ __align__(16) u16 As[64 * 72];
  __shared__ __align__(16) u16 Bs[64 * 72];
  const int tid = threadIdx.x;
  const int m0 = blockIdx.x * 64, n0 = blockIdx.y * 64;
  const int lane = tid & 63, wv = tid >> 6;
  const int fr = lane & 15, quad = lane >> 4;

  floatx4 acc[4];
#pragma unroll
  for (int i = 0; i < 4; ++i) acc[i] = (floatx4){0.f, 0.f, 0.f, 0.f};

  for (int kc = 0; kc < HH; kc += 64) {
    const u16* Ab = Hs + (u64)m0 * HH + kc;
#pragma unroll
    for (int it = 0; it < 2; ++it) {
      int linear = (it * 256 + tid) * 8;
      int r = linear >> 6, c = linear & 63;
      *(uint4*)&As[r * 72 + c] = *(const uint4*)(Ab + (u64)r * HH + c);
    }
    const u16* Bb = Wt + (u64)n0 * HH + kc;
#pragma unroll
    for (int it = 0; it < 2; ++it) {
      int linear = (it * 256 + tid) * 8;
      int n = linear >> 6, c = linear & 63;
      *(uint4*)&Bs[n * 72 + c] = *(const uint4*)(Bb + (u64)n * HH + c);
    }
    __syncthreads();
#pragma unroll
    for (int kk = 0; kk < 64; kk += 32) {
      frag8 bf = *(const frag8*)&Bs[(wv * 16 + fr) * 72 + kk + quad * 8];
#pragma unroll
      for (int i = 0; i < 4; ++i) {
        frag8 af = *(const frag8*)&As[(i * 16 + fr) * 72 + kk + quad * 8];
        acc[i] = __builtin_amdgcn_mfma_f32_16x16x32_bf16(af, bf, acc[i], 0, 0, 0);
      }
    }
    __syncthreads();
  }
  const int col = n0 + wv * 16 + fr;
#pragma unroll
  for (int i = 0; i < 4; ++i) {
#pragma unroll
    for (int r = 0; r < 4; ++r) {
      int m = m0 + i * 16 + quad * 4 + r;
      int t = m >> 8;       // m / BB
      int b = m & (BB - 1); // m % BB
      out[(u64)b * (TT * OO) + (u64)t * OO + col] = acc[i][r];
    }
  }
}

extern "C" void kernel_launch(void* const* d_in, const int* in_sizes, int n_in,
                              void* d_out, int out_size, void* d_ws, size_t ws_size,
                              hipStream_t stream) {
  (void)in_sizes; (void)n_in; (void)out_size; (void)ws_size;
  const float* x    = (const float*)d_in[0];
  const float* h0   = (const float*)d_in[1];
  const float* w_xh = (const float*)d_in[2];
  const float* w_hh = (const float*)d_in[3];
  const float* w_hy = (const float*)d_in[4];
  float* out = (float*)d_out;

  // workspace layout (bf16):
  //   S     : [TT+1][BB][HH]  state (slot 0 = h0; slot t+1 = Z_t then h_{t+1})
  //   Wxh_t : [HH][DD]   (aliased by scan flags after gemm_xh is done)
  //   Whh_t : [HH][HH]
  //   Why_t : [OO][HH]
  u16* S = (u16*)d_ws;
  u64 s_elems = (u64)(TT + 1) * BB * HH;
  u16* Wxh_t = S + s_elems;
  u16* Whh_t = Wxh_t + (u64)HH * DD;
  u16* Why_t = Whh_t + (u64)HH * HH;
  int* flags = (int*)Wxh_t;  // TT*8*32 ints = 512KB; Wxh_t (1MB) dead after gemm_xh
  const int n_flags = TT * 8 * 32;

  k_transpose<<<dim3((DD * HH + 255) / 256), dim3(256), 0, stream>>>(w_xh, Wxh_t, DD, HH);
  k_transpose<<<dim3((HH * HH + 255) / 256), dim3(256), 0, stream>>>(w_hh, Whh_t, HH, HH);
  k_transpose<<<dim3((HH * OO + 255) / 256), dim3(256), 0, stream>>>(w_hy, Why_t, HH, OO);
  k_init_s0<<<dim3(BB * HH / 256), dim3(256), 0, stream>>>(h0, S);

  k_gemm_xh<<<dim3((BB * TT) / 64, HH / 64), dim3(256), 0, stream>>>(x, Wxh_t, S);

  k_zero_flags<<<dim3((n_flags + 255) / 256), dim3(256), 0, stream>>>(flags, n_flags);

  k_scan<<<dim3(8, 32), dim3(256), 0, stream>>>(Whh_t, S, flags);

  k_gemm_hy<<<dim3((TT * BB) / 64, OO / 64), dim3(256), 0, stream>>>(
      S + (u64)BB * HH, Why_t, out);
  k_final_h<<<dim3(BB * HH / 256), dim3(256), 0, stream>>>(
      S + (u64)TT * BB * HH, out + (u64)BB * TT * OO);
}

// Round 2
// 3963.856 us; speedup vs baseline: 2.7924x; 2.7924x over previous
//
#include <hip/hip_runtime.h>
#include <hip/hip_bf16.h>

#define BB 256
#define TT 512
#define DD 512
#define HH 1024
#define OO 512

typedef unsigned short u16;
typedef unsigned int u32;
typedef unsigned long long u64;
typedef __attribute__((ext_vector_type(8))) short frag8;
typedef __attribute__((ext_vector_type(4))) float floatx4;

#define MFMA16 __builtin_amdgcn_mfma_f32_16x16x32_bf16

__device__ __forceinline__ u16 f2b(float f) {
  union { float f; u32 u; } v; v.f = f;
  u32 r = v.u + 0x7fffu + ((v.u >> 16) & 1u);
  return (u16)(r >> 16);
}
__device__ __forceinline__ float b2f(u16 b) {
  union { u32 u; float f; } v; v.u = ((u32)b) << 16; return v.f;
}
__device__ __forceinline__ float fast_tanh(float x) {
  float e = __expf(2.0f * x);
  return 1.0f - 2.0f / (e + 1.0f);
}
__device__ __forceinline__ frag8 mkfrag(u64 lo, u64 hi) {
  union { u64 d[2]; frag8 f; } u; u.d[0] = lo; u.d[1] = hi; return u.f;
}

// transpose f32 [K][N] -> bf16 [N][K]
__global__ void k_transpose(const float* __restrict__ src, u16* __restrict__ dst,
                            int K, int N) {
  int idx = blockIdx.x * 256 + threadIdx.x;
  if (idx >= K * N) return;
  int k = idx / N, n = idx - k * N;
  dst[(u64)n * K + k] = f2b(src[idx]);
}

__global__ void k_init_s0(const float* __restrict__ h0, u16* __restrict__ S) {
  int idx = blockIdx.x * 256 + threadIdx.x;
  if (idx < BB * HH) S[idx] = f2b(h0[idx]);
}

__global__ void k_final_h(const u16* __restrict__ Sl, float* __restrict__ out) {
  int idx = blockIdx.x * 256 + threadIdx.x;
  if (idx < BB * HH) out[idx] = b2f(Sl[idx]);
}

__global__ void k_zero_flags(int* __restrict__ flags, int n) {
  int idx = blockIdx.x * 256 + threadIdx.x;
  if (idx < n) flags[idx] = 0;
}

// ---------------------------------------------------------------------------
// GEMM1: Z = X @ W_xh.  X f32 [B*T, D] row-major (m = b*T + t).
// Wt bf16 [N=HH][K=DD].  Output scattered bf16 into S[t+1][b][col].
// ---------------------------------------------------------------------------
__global__ __launch_bounds__(256) void k_gemm_xh(const float* __restrict__ X,
                                                 const u16* __restrict__ Wt,
                                                 u16* __restrict__ S) {
  __shared__ __align__(16) u16 As[64 * 72];
  __shared__ __align__(16) u16 Bs[64 * 72];
  const int tid = threadIdx.x;
  const int m0 = blockIdx.x * 64, n0 = blockIdx.y * 64;
  const int lane = tid & 63, wv = tid >> 6;
  const int fr = lane & 15, quad = lane >> 4;

  floatx4 acc[4];
#pragma unroll
  for (int i = 0; i < 4; ++i) acc[i] = (floatx4){0.f, 0.f, 0.f, 0.f};

  for (int kc = 0; kc < DD; kc += 64) {
    const float* Ab = X + (u64)m0 * DD + kc;
#pragma unroll
    for (int it = 0; it < 4; ++it) {
      int linear = (it * 256 + tid) * 4;
      int r = linear >> 6, c = linear & 63;
      float4 v = *(const float4*)(Ab + (u64)r * DD + c);
      ushort4 o;
      o.x = f2b(v.x); o.y = f2b(v.y); o.z = f2b(v.z); o.w = f2b(v.w);
      *(ushort4*)&As[r * 72 + c] = o;
    }
    const u16* Bb = Wt + (u64)n0 * DD + kc;
#pragma unroll
    for (int it = 0; it < 2; ++it) {
      int linear = (it * 256 + tid) * 8;
      int n = linear >> 6, c = linear & 63;
      *(uint4*)&Bs[n * 72 + c] = *(const uint4*)(Bb + (u64)n * DD + c);
    }
    __syncthreads();
#pragma unroll
    for (int kk = 0; kk < 64; kk += 32) {
      frag8 bf = *(const frag8*)&Bs[(wv * 16 + fr) * 72 + kk + quad * 8];
#pragma unroll
      for (int i = 0; i < 4; ++i) {
        frag8 af = *(const frag8*)&As[(i * 16 + fr) * 72 + kk + quad * 8];
        acc[i] = MFMA16(af, bf, acc[i], 0, 0, 0);
      }
    }
    __syncthreads();
  }
  const int col = n0 + wv * 16 + fr;
#pragma unroll
  for (int i = 0; i < 4; ++i) {
#pragma unroll
    for (int r = 0; r < 4; ++r) {
      int m = m0 + i * 16 + quad * 4 + r;
      int t = m & (TT - 1);
      int b = m >> 9;  // m / TT
      S[((u64)(t + 1) * BB + b) * HH + col] = f2b(acc[i][r]);
    }
  }
}

// ---------------------------------------------------------------------------
// Persistent scan: for t in 0..TT: S[t+1] = tanh(S[t] @ W_hh + S[t+1])
// Grid 8x32 = 256 blocks (1/CU). Block (mb,nb) owns rows mb*32..+32,
// cols nb*32..+32 for all steps. W_hh slice LDS-resident (v1 structure).
//
// v3 sync: ZERO cache-maintenance ops (no wbl2, no inv) in the whole loop.
//  - All cross-block data (h stores, A gathers, flags) moves via relaxed
//    agent-scope atomics -> sc0 sc1 accesses that bypass the non-coherent
//    per-XCD L2 and hit the shared Infinity Cache (coherent point).
//  - Producer order: data stores -> __syncthreads (each wave drains
//    vmcnt(0) before s_barrier) -> tid0 relaxed flag store.
//  - Consumer: 8 lanes/wave poll this wave's 8 producers (relaxed loads,
//    no invalidate); workgroup acquire fence = compiler ordering only.
//  - Z prefetched with normal loads before the spin (written once by
//    gemm_xh pre-kernel; no coherence hazard).
// ---------------------------------------------------------------------------
__global__ __launch_bounds__(256) void k_scan(const u16* __restrict__ Whh_t,
                                              u16* __restrict__ S,
                                              int* __restrict__ flags) {
  extern __shared__ __align__(16) u16 smem[];
  u16* Ws = smem;                           // [32][1032] bf16 (66048 B)
  float* Red = (float*)(smem + 32 * 1032);  // [4][32][33] f32 (16896 B)

  const int tid = threadIdx.x;
  const int mb = blockIdx.x;   // 0..7  (row block)
  const int nb = blockIdx.y;   // 0..31 (col block)
  const int m0 = mb * 32, n0 = nb * 32;
  const int lane = tid & 63, wv = tid >> 6;
  const int fr = lane & 15, q = lane >> 4;
  const int kbase = wv * 256;
  const int er = tid >> 4;         // 0..15 (epilogue row)
  const int ec = (tid & 15) * 2;   // 0..30 (epilogue col pair)

  // Stage resident W slice: rows n0..n0+32 of Whh_t [n][k], full K=1024.
  {
    const u16* Wb = Whh_t + (u64)n0 * HH;
#pragma unroll
    for (int it = 0; it < 16; ++it) {
      int linear = (it * 256 + tid) * 8;
      int r = linear >> 10, c = linear & 1023;
      *(uint4*)&Ws[r * 1032 + c] = *(const uint4*)(Wb + (u64)r * HH + c);
    }
  }
  __syncthreads();

  for (int t = 0; t < TT; ++t) {
    u16* Sout = S + (u64)(t + 1) * BB * HH + (u64)m0 * HH + n0;

    // Z prefetch (own tile; written by gemm_xh before this kernel).
    u32 z01 = *(const u32*)(Sout + (u64)er * HH + ec);
    u32 z23 = *(const u32*)(Sout + (u64)(er + 16) * HH + ec);
    asm volatile("" :: "v"(z01), "v"(z23));  // pin issue before the spin

    if (t > 0) {
      // Wave wv consumes k in [wv*256, wv*256+256) of S[t] = tiles from
      // producers (mb, nb' = wv*8 .. wv*8+7) at step t-1.
      int* fb = flags + ((u64)(t - 1) * 8 + mb) * 32;
      if (lane < 8) {
        while (__hip_atomic_load(&fb[wv * 8 + lane], __ATOMIC_RELAXED,
                                 __HIP_MEMORY_SCOPE_AGENT) == 0) {
          __builtin_amdgcn_s_sleep(2);
        }
      }
      // Compiler-level ordering only (no cache ops at workgroup scope):
      // keeps the A gathers below from hoisting above the poll.
      __builtin_amdgcn_fence(__ATOMIC_ACQUIRE, "workgroup");
    }

    // Gather A fragments straight to VGPRs via device-coherent (sc0 sc1)
    // relaxed atomic loads -> served by the Infinity Cache, fresh data,
    // no invalidate needed. 16B per (row, kt) split into 2x8B.
    const u16* St = S + (u64)t * BB * HH;
    const u64* A0p = (const u64*)(St + (u64)(m0 + fr) * HH + kbase + q * 8);
    const u64* A1p = (const u64*)(St + (u64)(m0 + 16 + fr) * HH + kbase + q * 8);
    u64 a0[16], a1[16];
#pragma unroll
    for (int kt = 0; kt < 8; ++kt) {
      a0[2 * kt]     = __hip_atomic_load(A0p + kt * 8,     __ATOMIC_RELAXED, __HIP_MEMORY_SCOPE_AGENT);
      a0[2 * kt + 1] = __hip_atomic_load(A0p + kt * 8 + 1, __ATOMIC_RELAXED, __HIP_MEMORY_SCOPE_AGENT);
      a1[2 * kt]     = __hip_atomic_load(A1p + kt * 8,     __ATOMIC_RELAXED, __HIP_MEMORY_SCOPE_AGENT);
      a1[2 * kt + 1] = __hip_atomic_load(A1p + kt * 8 + 1, __ATOMIC_RELAXED, __HIP_MEMORY_SCOPE_AGENT);
    }

    floatx4 acc[2][2];
#pragma unroll
    for (int i = 0; i < 2; ++i)
#pragma unroll
      for (int j = 0; j < 2; ++j) acc[i][j] = (floatx4){0.f, 0.f, 0.f, 0.f};

#pragma unroll
    for (int kt = 0; kt < 8; ++kt) {
      const int k = kbase + kt * 32 + q * 8;
      frag8 b0 = *(const frag8*)&Ws[fr * 1032 + k];
      frag8 b1 = *(const frag8*)&Ws[(16 + fr) * 1032 + k];
      frag8 af0 = mkfrag(a0[2 * kt], a0[2 * kt + 1]);
      frag8 af1 = mkfrag(a1[2 * kt], a1[2 * kt + 1]);
      acc[0][0] = MFMA16(af0, b0, acc[0][0], 0, 0, 0);
      acc[0][1] = MFMA16(af0, b1, acc[0][1], 0, 0, 0);
      acc[1][0] = MFMA16(af1, b0, acc[1][0], 0, 0, 0);
      acc[1][1] = MFMA16(af1, b1, acc[1][1], 0, 0, 0);
    }

    // Per-wave K-split partials -> LDS
#pragma unroll
    for (int im = 0; im < 2; ++im)
#pragma unroll
      for (int in = 0; in < 2; ++in)
#pragma unroll
        for (int r = 0; r < 4; ++r) {
          int row = im * 16 + q * 4 + r;
          int col = in * 16 + fr;
          Red[((u64)wv * 32 + row) * 33 + col] = acc[im][in][r];
        }
    __syncthreads();

    // Reduce 4 partials, add prefetched Z, tanh, store packed bf16 pairs
    // with device-coherent (sc0 sc1) stores.
    float s00 = Red[(0 * 32 + er) * 33 + ec]     + Red[(1 * 32 + er) * 33 + ec] +
                Red[(2 * 32 + er) * 33 + ec]     + Red[(3 * 32 + er) * 33 + ec];
    float s01 = Red[(0 * 32 + er) * 33 + ec + 1] + Red[(1 * 32 + er) * 33 + ec + 1] +
                Red[(2 * 32 + er) * 33 + ec + 1] + Red[(3 * 32 + er) * 33 + ec + 1];
    float s10 = Red[(0 * 32 + er + 16) * 33 + ec]     + Red[(1 * 32 + er + 16) * 33 + ec] +
                Red[(2 * 32 + er + 16) * 33 + ec]     + Red[(3 * 32 + er + 16) * 33 + ec];
    float s11 = Red[(0 * 32 + er + 16) * 33 + ec + 1] + Red[(1 * 32 + er + 16) * 33 + ec + 1] +
                Red[(2 * 32 + er + 16) * 33 + ec + 1] + Red[(3 * 32 + er + 16) * 33 + ec + 1];
    float z0 = b2f((u16)(z01 & 0xffffu)), z1 = b2f((u16)(z01 >> 16));
    float z2 = b2f((u16)(z23 & 0xffffu)), z3 = b2f((u16)(z23 >> 16));
    u32 p0 = (u32)f2b(fast_tanh(s00 + z0)) | ((u32)f2b(fast_tanh(s01 + z1)) << 16);
    u32 p1 = (u32)f2b(fast_tanh(s10 + z2)) | ((u32)f2b(fast_tanh(s11 + z3)) << 16);
    __hip_atomic_store((u32*)(Sout + (u64)er * HH + ec), p0,
                       __ATOMIC_RELAXED, __HIP_MEMORY_SCOPE_AGENT);
    __hip_atomic_store((u32*)(Sout + (u64)(er + 16) * HH + ec), p1,
                       __ATOMIC_RELAXED, __HIP_MEMORY_SCOPE_AGENT);
    __syncthreads();  // every wave drains vmcnt(0) before s_barrier

    if (tid == 0) {
      __hip_atomic_store(&flags[((u64)t * 8 + mb) * 32 + nb], 1,
                         __ATOMIC_RELAXED, __HIP_MEMORY_SCOPE_AGENT);
    }
  }
}

// ---------------------------------------------------------------------------
// GEMM3: Y = Hs @ W_hy.  Hs bf16 [T*B][HH] (m = t*B + b), Wt bf16 [OO][HH].
// ---------------------------------------------------------------------------
__global__ __launch_bounds__(256) void k_gemm_hy(const u16* __restrict__ Hs,
                                                 const u16* __restrict__ Wt,
                                                 float* __restrict__ out) {
  __shared__ __align__(16) u16 As[64 * 72];
  __shared__ __align__(16) u16 Bs[64 * 72];
  const int tid = threadIdx.x;
  const int m0 = blockIdx.x * 64, n0 = blockIdx.y * 64;
  const int lane = tid & 63, wv = tid >> 6;
  const int fr = lane & 15, quad = lane >> 4;

  floatx4 acc[4];
#pragma unroll
  for (int i = 0; i < 4; ++i) acc[i] = (floatx4){0.f, 0.f, 0.f, 0.f};

  for (int kc = 0; kc < HH; kc += 64) {
    const u16* Ab = Hs + (u64)m0 * HH + kc;
#pragma unroll
    for (int it = 0; it < 2; ++it) {
      int linear = (it * 256 + tid) * 8;
      int r = linear >> 6, c = linear & 63;
      *(uint4*)&As[r * 72 + c] = *(const uint4*)(Ab + (u64)r * HH + c);
    }
    const u16* Bb = Wt + (u64)n0 * HH + kc;
#pragma unroll
    for (int it = 0; it < 2; ++it) {
      int linear = (it * 256 + tid) * 8;
      int n = linear >> 6, c = linear & 63;
      *(uint4*)&Bs[n * 72 + c] = *(const uint4*)(Bb + (u64)n * HH + c);
    }
    __syncthreads();
#pragma unroll
    for (int kk = 0; kk < 64; kk += 32) {
      frag8 bf = *(const frag8*)&Bs[(wv * 16 + fr) * 72 + kk + quad * 8];
#pragma unroll
      for (int i = 0; i < 4; ++i) {
        frag8 af = *(const frag8*)&As[(i * 16 + fr) * 72 + kk + quad * 8];
        acc[i] = MFMA16(af, bf, acc[i], 0, 0, 0);
      }
    }
    __syncthreads();
  }
  const int col = n0 + wv * 16 + fr;
#pragma unroll
  for (int i = 0; i < 4; ++i) {
#pragma unroll
    for (int r = 0; r < 4; ++r) {
      int m = m0 + i * 16 + quad * 4 + r;
      int t = m >> 8;       // m / BB
      int b = m & (BB - 1); // m % BB
      out[(u64)b * (TT * OO) + (u64)t * OO + col] = acc[i][r];
    }
  }
}

extern "C" void kernel_launch(void* const* d_in, const int* in_sizes, int n_in,
                              void* d_out, int out_size, void* d_ws, size_t ws_size,
                              hipStream_t stream) {
  (void)in_sizes; (void)n_in; (void)out_size; (void)ws_size;
  const float* x    = (const float*)d_in[0];
  const float* h0   = (const float*)d_in[1];
  const float* w_xh = (const float*)d_in[2];
  const float* w_hh = (const float*)d_in[3];
  const float* w_hy = (const float*)d_in[4];
  float* out = (float*)d_out;

  // workspace layout (bf16):
  //   S     : [TT+1][BB][HH]  state (slot 0 = h0; slot t+1 = Z_t then h_{t+1})
  //   Wxh_t : [HH][DD]   (aliased by scan flags after gemm_xh is done)
  //   Whh_t : [HH][HH]
  //   Why_t : [OO][HH]
  u16* S = (u16*)d_ws;
  u64 s_elems = (u64)(TT + 1) * BB * HH;
  u16* Wxh_t = S + s_elems;
  u16* Whh_t = Wxh_t + (u64)HH * DD;
  u16* Why_t = Whh_t + (u64)HH * HH;
  int* flags = (int*)Wxh_t;  // TT*8*32 ints = 512KB; Wxh_t (1MB) dead after gemm_xh
  const int n_flags = TT * 8 * 32;

  k_transpose<<<dim3((DD * HH + 255) / 256), dim3(256), 0, stream>>>(w_xh, Wxh_t, DD, HH);
  k_transpose<<<dim3((HH * HH + 255) / 256), dim3(256), 0, stream>>>(w_hh, Whh_t, HH, HH);
  k_transpose<<<dim3((HH * OO + 255) / 256), dim3(256), 0, stream>>>(w_hy, Why_t, HH, OO);
  k_init_s0<<<dim3(BB * HH / 256), dim3(256), 0, stream>>>(h0, S);

  k_gemm_xh<<<dim3((BB * TT) / 64, HH / 64), dim3(256), 0, stream>>>(x, Wxh_t, S);

  k_zero_flags<<<dim3((n_flags + 255) / 256), dim3(256), 0, stream>>>(flags, n_flags);

  const int scan_lds = 32 * 1032 * 2 + 4 * 32 * 33 * 4;  // 82944 B
  hipFuncSetAttribute((const void*)k_scan,
                      hipFuncAttributeMaxDynamicSharedMemorySize, scan_lds);
  k_scan<<<dim3(8, 32), dim3(256), scan_lds, stream>>>(Whh_t, S, flags);

  k_gemm_hy<<<dim3((TT * BB) / 64, OO / 64), dim3(256), 0, stream>>>(
      S + (u64)BB * HH, Why_t, out);
  k_final_h<<<dim3(BB * HH / 256), dim3(256), 0, stream>>>(
      S + (u64)TT * BB * HH, out + (u64)BB * TT * OO);
}